// Round 3
// baseline (666.786 us; speedup 1.0000x reference)
//
#include <hip/hip_runtime.h>

#define B_    64
#define T_    256
#define TA_   255
#define OBS_  512
#define ACT_  32
#define LAT_  64
#define NB_   8
#define BS_   8
#define PHI_  512
#define BT_   16384
#define BTA_  16320
#define CH_   8
#define NCH_  32

// output layout (floats): latent | rho | predicted_latents | predicted_obs
#define RHO_OFF   1048576ULL
#define PL_OFF    67895296ULL
#define POBS_OFF  68943872ULL

typedef float f32x4 __attribute__((ext_vector_type(4)));

// ---------------- encoder: latent = obs @ W_enc + b_enc ----------------
// 64x64 output tile, K chunked by 64 through LDS. Per-lane (divergent)
// addresses everywhere -> vector loads (round-1 lesson: wave-uniform
// addresses become s_load and thrash the scalar cache at 33 MB).
__global__ __launch_bounds__(256) void enc_kernel(
    const float* __restrict__ obs, const float* __restrict__ W,
    const float* __restrict__ bias, float* __restrict__ latent)
{
    __shared__ float At[64][68];   // At[k][row], pad 68: read = 2-way (free)
    __shared__ float Wt[64][64];   // Wt[k][col]
    const int tid = threadIdx.x;
    const int c0 = (tid & 15) * 4;
    const int r0 = (tid >> 4) * 4;
    const int row0 = blockIdx.x * 64;

    float4 pa[4], pw[4];
    // prefetch chunk 0
#pragma unroll
    for (int j = 0; j < 4; ++j) {
        int ft = tid + j * 256;
        int k4 = ft & 15, r = ft >> 4;
        pa[j] = *(const float4*)(obs + (size_t)(row0 + r) * OBS_ + k4 * 4);
        int c4 = ft & 15, kk = ft >> 4;
        pw[j] = *(const float4*)(W + (size_t)kk * LAT_ + c4 * 4);
    }

    float acc[4][4];
    float4 bv = *(const float4*)(bias + c0);
#pragma unroll
    for (int i = 0; i < 4; ++i) {
        acc[i][0] = bv.x; acc[i][1] = bv.y; acc[i][2] = bv.z; acc[i][3] = bv.w;
    }

    for (int kc = 0; kc < OBS_; kc += 64) {
#pragma unroll
        for (int j = 0; j < 4; ++j) {
            int ft = tid + j * 256;
            int k4 = ft & 15, r = ft >> 4;
            At[k4 * 4 + 0][r] = pa[j].x;
            At[k4 * 4 + 1][r] = pa[j].y;
            At[k4 * 4 + 2][r] = pa[j].z;
            At[k4 * 4 + 3][r] = pa[j].w;
            int c4 = ft & 15, kk = ft >> 4;
            *(float4*)(&Wt[kk][c4 * 4]) = pw[j];
        }
        __syncthreads();
        if (kc + 64 < OBS_) {
            // prefetch next chunk while computing this one
#pragma unroll
            for (int j = 0; j < 4; ++j) {
                int ft = tid + j * 256;
                int k4 = ft & 15, r = ft >> 4;
                pa[j] = *(const float4*)(obs + (size_t)(row0 + r) * OBS_ + kc + 64 + k4 * 4);
                int c4 = ft & 15, kk = ft >> 4;
                pw[j] = *(const float4*)(W + (size_t)(kc + 64 + kk) * LAT_ + c4 * 4);
            }
        }
#pragma unroll 4
        for (int kk = 0; kk < 64; ++kk) {
            float4 a = *(const float4*)(&At[kk][r0]);
            float4 w = *(const float4*)(&Wt[kk][c0]);
            acc[0][0] = fmaf(a.x, w.x, acc[0][0]); acc[0][1] = fmaf(a.x, w.y, acc[0][1]);
            acc[0][2] = fmaf(a.x, w.z, acc[0][2]); acc[0][3] = fmaf(a.x, w.w, acc[0][3]);
            acc[1][0] = fmaf(a.y, w.x, acc[1][0]); acc[1][1] = fmaf(a.y, w.y, acc[1][1]);
            acc[1][2] = fmaf(a.y, w.z, acc[1][2]); acc[1][3] = fmaf(a.y, w.w, acc[1][3]);
            acc[2][0] = fmaf(a.z, w.x, acc[2][0]); acc[2][1] = fmaf(a.z, w.y, acc[2][1]);
            acc[2][2] = fmaf(a.z, w.z, acc[2][2]); acc[2][3] = fmaf(a.z, w.w, acc[2][3]);
            acc[3][0] = fmaf(a.w, w.x, acc[3][0]); acc[3][1] = fmaf(a.w, w.y, acc[3][1]);
            acc[3][2] = fmaf(a.w, w.z, acc[3][2]); acc[3][3] = fmaf(a.w, w.w, acc[3][3]);
        }
        __syncthreads();
    }
#pragma unroll
    for (int i = 0; i < 4; ++i)
        *(float4*)(latent + (size_t)(row0 + r0 + i) * LAT_ + c0) =
            make_float4(acc[i][0], acc[i][1], acc[i][2], acc[i][3]);
}

// ---------------- 8x8 matmul in registers ----------------
__device__ __forceinline__ void mm8(float* __restrict__ D,
                                    const float* __restrict__ X,
                                    const float* __restrict__ Y)
{
#pragma unroll
    for (int r = 0; r < 8; ++r)
#pragma unroll
        for (int c = 0; c < 8; ++c) {
            float s = 0.f;
#pragma unroll
            for (int q = 0; q < 8; ++q) s = fmaf(X[r * 8 + q], Y[q * 8 + c], s);
            D[r * 8 + c] = s;
        }
}

// ---------------- phi GEMM + expm, one 8x8 block per thread ----------------
// In-place Horner via right-multiply (A and p(A) commute); live set
// A+P+row ~= 145 regs. (256,1) -> 512-VGPR cap, no spill bucket.
// R5: writes rho ROWS directly (its 8x8 block + 56 zeros per row; each
// lane owns a contiguous 2KB span). R6 post-mortem: the NT hint on the
// zero stores evicted lines between the 8 partial 16B writes -> 1.9GB of
// line-fill RMW fetch + 2.3x write amplification. PLAIN stores let L2
// byte-merge the partials; line evicts once, fully dirty, no fill.
__global__ __launch_bounds__(256, 1) void phi_expm_kernel(
    const float* __restrict__ act, const float* __restrict__ Wp,
    const float* __restrict__ bp, float* __restrict__ rho)
{
    const int bt = blockIdx.x * 256 + threadIdx.x;
    const int k  = blockIdx.y;
    if (bt >= BTA_) return;

    float A[64];
    {
        const float* bpp = bp + k * 64;
#pragma unroll
        for (int p = 0; p < 64; ++p) A[p] = bpp[p];
    }
    const float4* arow4 = (const float4*)(act + (size_t)bt * ACT_);
    const float* wk = Wp + k * 64;
#pragma unroll
    for (int a4 = 0; a4 < ACT_ / 4; ++a4) {
        float4 av = arow4[a4];
        const float* wr = wk + (size_t)(a4 * 4) * PHI_;
#pragma unroll
        for (int p = 0; p < 64; ++p) A[p] = fmaf(av.x, wr[p], A[p]);
        wr += PHI_;
#pragma unroll
        for (int p = 0; p < 64; ++p) A[p] = fmaf(av.y, wr[p], A[p]);
        wr += PHI_;
#pragma unroll
        for (int p = 0; p < 64; ++p) A[p] = fmaf(av.z, wr[p], A[p]);
        wr += PHI_;
#pragma unroll
        for (int p = 0; p < 64; ++p) A[p] = fmaf(av.w, wr[p], A[p]);
    }

    // in-place scale+transpose: A <- (block^T)/8 (reference transposes blocks;
    // scaling-and-squaring with s=3)
#pragma unroll
    for (int r = 0; r < 8; ++r) {
        A[r * 9] *= 0.125f;
#pragma unroll
        for (int c = r + 1; c < 8; ++c) {
            float t = A[r * 8 + c];
            A[r * 8 + c] = 0.125f * A[c * 8 + r];
            A[c * 8 + r] = 0.125f * t;
        }
    }

    // degree-7 Taylor, Horner with right-multiply, P updated IN PLACE:
    // P = A/7! + I/6!; then 6x (P = P*A + c I), c = 1/120,1/24,1/6,1/2,1,1
    float P[64];
#pragma unroll
    for (int i = 0; i < 64; ++i) P[i] = (1.f / 5040.f) * A[i];
#pragma unroll
    for (int d = 0; d < 8; ++d) P[d * 9] += 1.f / 720.f;

    constexpr float COEF[6] = {1.f/120.f, 1.f/24.f, 1.f/6.f, 0.5f, 1.f, 1.f};
#pragma unroll
    for (int it = 0; it < 6; ++it) {
        const float coef = COEF[it];
#pragma unroll
        for (int r = 0; r < 8; ++r) {
            float t[8];
#pragma unroll
            for (int c = 0; c < 8; ++c) {
                float s = 0.f;
#pragma unroll
                for (int q = 0; q < 8; ++q) s = fmaf(P[r * 8 + q], A[q * 8 + c], s);
                t[c] = s;
            }
#pragma unroll
            for (int c = 0; c < 8; ++c) P[r * 8 + c] = t[c];
            P[r * 9] += coef;
        }
    }

    // 3 squarings, ping-pong (A is dead; T reuses its registers): result in T
    float T[64];
    mm8(T, P, P);
    mm8(P, T, T);
    mm8(T, P, P);

    // write rows k*8..k*8+8 of rho[bt] IN FULL: this thread owns them
    // entirely (diag block at cols k*8..k*8+8, zeros elsewhere). k is
    // blockIdx.y -> the c4 compares below are wave-uniform. Plain stores:
    // each lane fills its 128B lines with 8 consecutive 16B writes that
    // merge in L2 (byte-granular dirty), no fill, no amplification.
    float* base = rho + ((size_t)bt * LAT_ + (size_t)(k * BS_)) * LAT_;
    const f32x4 z = {0.f, 0.f, 0.f, 0.f};
#pragma unroll
    for (int r = 0; r < 8; ++r) {
        f32x4* rp = (f32x4*)(base + (size_t)r * LAT_);
#pragma unroll
        for (int c4 = 0; c4 < 16; ++c4) {
            if (c4 == 2 * k) {
                f32x4 v = {T[r*8+0], T[r*8+1], T[r*8+2], T[r*8+3]};
                rp[c4] = v;
            } else if (c4 == 2 * k + 1) {
                f32x4 v = {T[r*8+4], T[r*8+5], T[r*8+6], T[r*8+7]};
                rp[c4] = v;
            } else {
                rp[c4] = z;
            }
        }
    }
}

// ---------------- 8x8 block load from strided rows ----------------
__device__ __forceinline__ void load_block8(float* __restrict__ dst,
                                            const float* __restrict__ p, int rs)
{
#pragma unroll
    for (int r = 0; r < 8; ++r) {
        float4 x = *(const float4*)(p + (size_t)r * rs);
        float4 y = *(const float4*)(p + (size_t)r * rs + 4);
        dst[r*8+0] = x.x; dst[r*8+1] = x.y; dst[r*8+2] = x.z; dst[r*8+3] = x.w;
        dst[r*8+4] = y.x; dst[r*8+5] = y.y; dst[r*8+6] = y.z; dst[r*8+7] = y.w;
    }
}

// ======== parallel scan over the recurrence h_{t+1} = h_t * M_t ========
// Phase A: per (b,k,chunk) local prefix products L_i = M_{t0}...M_{t0+i}
// (64,1) keeps the 512-VGPR cap (~150 live). Reads the diag blocks
// straight out of rho (L2-hot, written by phi just before); 256 blocks
// x 64 so all 256 CUs participate. pfx stays COMPACT (64 floats/block)
// so phases B/C keep dense reads.
#define SL_BODY_(I)                                                           \
    {                                                                         \
        float M[64];                                                          \
        load_block8(M, src + (size_t)(I) * 4096, LAT_);                       \
        _Pragma("unroll")                                                     \
        for (int r = 0; r < 8; ++r) {                                         \
            float tmp[8];                                                     \
            _Pragma("unroll")                                                 \
            for (int c = 0; c < 8; ++c) {                                     \
                float s = 0.f;                                                \
                _Pragma("unroll")                                             \
                for (int q = 0; q < 8; ++q)                                   \
                    s = fmaf(R[r * 8 + q], M[q * 8 + c], s);                  \
                tmp[c] = s;                                                   \
            }                                                                 \
            _Pragma("unroll")                                                 \
            for (int c = 0; c < 8; ++c) R[r * 8 + c] = tmp[c];                \
        }                                                                     \
        float* dp = dst + (size_t)(I) * 512;                                  \
        _Pragma("unroll")                                                     \
        for (int q = 0; q < 16; ++q) ((float4*)dp)[q] = ((const float4*)R)[q];\
    }

__global__ __launch_bounds__(64, 1) void scan_local_kernel(
    const float* __restrict__ rho, float* __restrict__ pfx)
{
    const int tid = blockIdx.x * 64 + threadIdx.x;   // 16384 threads
    const int k = tid & 7;
    const int j = (tid >> 3) & 31;
    const int b = tid >> 8;
    const int t0 = j * CH_;
    const int cnt = (TA_ - t0 < CH_) ? (TA_ - t0) : CH_;   // 8 (7 for last chunk)
    // diag block top-left of rho[b, t0], block k
    const float* src = rho + (size_t)(b * TA_ + t0) * 4096 + (size_t)k * (BS_ * LAT_ + BS_);
    float*       dst = pfx + ((size_t)(b * TA_ + t0) * 8 + k) * 64;

    float R[64];
    load_block8(R, src, LAT_);
#pragma unroll
    for (int q = 0; q < 16; ++q) ((float4*)dst)[q] = ((const float4*)R)[q];

    if (cnt == CH_) {
#pragma unroll
        for (int i = 1; i < CH_; ++i) SL_BODY_(i);
    } else {
#pragma unroll
        for (int i = 1; i < CH_ - 1; ++i) SL_BODY_(i);   // cnt is always 7 here
    }
}
#undef SL_BODY_

// Phase B: per (b,k) scan of chunk totals -> g_j = h0 * M_0..M_{CH*j-1}; pl[:,0]
// (64,1): live C+Cn+g ~= 140 regs needs the 512 cap too. Next-chunk prefetch.
__global__ __launch_bounds__(64, 1) void scan_chunk_kernel(
    const float* __restrict__ latent, const float* __restrict__ pfx,
    float* __restrict__ gws, float* __restrict__ pl)
{
    const int tid = blockIdx.x * 64 + threadIdx.x;   // 512 threads
    const int k = tid & 7, b = tid >> 3;
    float g[8];
    const float* l0 = latent + (size_t)b * T_ * LAT_ + k * 8;
#pragma unroll
    for (int m = 0; m < 8; ++m) g[m] = l0[m];

    float* pl0 = pl + (size_t)b * T_ * LAT_ + k * 8;
    *(float4*)(pl0)     = make_float4(g[0], g[1], g[2], g[3]);
    *(float4*)(pl0 + 4) = make_float4(g[4], g[5], g[6], g[7]);

    float* gp = gws + ((size_t)(b * NCH_) * 8 + k) * 8;
    *(float4*)(gp)     = make_float4(g[0], g[1], g[2], g[3]);
    *(float4*)(gp + 4) = make_float4(g[4], g[5], g[6], g[7]);

    float C[64];
    {
        const float* cp = pfx + ((size_t)(b * TA_ + CH_ - 1) * 8 + k) * 64;
#pragma unroll
        for (int q = 0; q < 16; ++q) ((float4*)C)[q] = ((const float4*)cp)[q];
    }
    for (int j = 1; j < NCH_; ++j) {
        float Cn[64];
        if (j + 1 < NCH_) {
            const float* cp = pfx + ((size_t)(b * TA_ + (j + 1) * CH_ - 1) * 8 + k) * 64;
#pragma unroll
            for (int q = 0; q < 16; ++q) ((float4*)Cn)[q] = ((const float4*)cp)[q];
        }
        float ng[8];
#pragma unroll
        for (int m = 0; m < 8; ++m) {
            float s = 0.f;
#pragma unroll
            for (int l = 0; l < 8; ++l) s = fmaf(g[l], C[l * 8 + m], s);
            ng[m] = s;
        }
#pragma unroll
        for (int m = 0; m < 8; ++m) g[m] = ng[m];
        float* gq = gws + ((size_t)(b * NCH_ + j) * 8 + k) * 8;
        *(float4*)(gq)     = make_float4(g[0], g[1], g[2], g[3]);
        *(float4*)(gq + 4) = make_float4(g[4], g[5], g[6], g[7]);
#pragma unroll
        for (int q = 0; q < 64; ++q) C[q] = Cn[q];
    }
}

// Phase C: per (b,t,k): h_t = g_j * L_{j,i}  -> pl[b,t+1,k*8..]
__global__ __launch_bounds__(256, 1) void scan_emit_kernel(
    const float* __restrict__ pfx, const float* __restrict__ gws,
    float* __restrict__ pl)
{
    const int tid = blockIdx.x * 256 + threadIdx.x;   // 130560 threads
    const int k = tid & 7;
    const int bt = tid >> 3;            // 0..16319
    const int b = bt / TA_;
    const int t = bt - b * TA_;
    const int j = t >> 3;               // CH_ = 8

    float g[8];
    const float* gp = gws + ((size_t)(b * NCH_ + j) * 8 + k) * 8;
    *(float4*)(g)     = *(const float4*)(gp);
    *(float4*)(g + 4) = *(const float4*)(gp + 4);

    const float* lp = pfx + ((size_t)bt * 8 + k) * 64;
    float L[64];
#pragma unroll
    for (int q = 0; q < 16; ++q) ((float4*)L)[q] = ((const float4*)lp)[q];

    float h[8];
#pragma unroll
    for (int m = 0; m < 8; ++m) {
        float s = 0.f;
#pragma unroll
        for (int l = 0; l < 8; ++l) s = fmaf(g[l], L[l * 8 + m], s);
        h[m] = s;
    }
    float* op = pl + ((size_t)b * T_ + t + 1) * LAT_ + k * 8;
    *(float4*)(op)     = make_float4(h[0], h[1], h[2], h[3]);
    *(float4*)(op + 4) = make_float4(h[4], h[5], h[6], h[7]);
}

// ---------------- sequential recurrence (fallback for small ws) ----------------
// reads the diag blocks straight out of rho (always valid now)
__global__ __launch_bounds__(64) void recur_kernel(
    const float* __restrict__ latent, const float* __restrict__ rho,
    float* __restrict__ pl)
{
    const int tid = blockIdx.x * 64 + threadIdx.x;   // 0..511
    const int b = tid >> 3, k = tid & 7;
    const float* e = rho + (size_t)b * ((size_t)TA_ * 4096) + (size_t)k * (BS_ * LAT_ + BS_);

    float h[8];
    const float* l0 = latent + (size_t)b * T_ * LAT_ + k * 8;
#pragma unroll
    for (int j = 0; j < 8; ++j) h[j] = l0[j];
    float* plp = pl + (size_t)b * T_ * LAT_ + k * 8;
    *(float4*)(plp)     = make_float4(h[0], h[1], h[2], h[3]);
    *(float4*)(plp + 4) = make_float4(h[4], h[5], h[6], h[7]);

    float eA[64], eB[64];
    load_block8(eA, e, LAT_);

#define STEP_(EBUF)                                                          \
    {                                                                        \
        float nh[8];                                                         \
        _Pragma("unroll")                                                    \
        for (int c = 0; c < 8; ++c) {                                        \
            float s = 0.f;                                                   \
            _Pragma("unroll")                                                \
            for (int r = 0; r < 8; ++r) s = fmaf(h[r], EBUF[r * 8 + c], s);  \
            nh[c] = s;                                                       \
        }                                                                    \
        plp += LAT_;                                                         \
        *(float4*)(plp)     = make_float4(nh[0], nh[1], nh[2], nh[3]);       \
        *(float4*)(plp + 4) = make_float4(nh[4], nh[5], nh[6], nh[7]);       \
        _Pragma("unroll")                                                    \
        for (int j = 0; j < 8; ++j) h[j] = nh[j];                            \
    }

    for (int t = 0; t < TA_; t += 2) {
        int tn = (t + 1 < TA_) ? t + 1 : TA_ - 1;
        load_block8(eB, e + (size_t)tn * 4096, LAT_);
        STEP_(eA);
        if (t + 1 >= TA_) break;
        int tn2 = (t + 2 < TA_) ? t + 2 : TA_ - 1;
        load_block8(eA, e + (size_t)tn2 * 4096, LAT_);
        STEP_(eB);
    }
#undef STEP_
}

// ---------------- decoder: pobs = pl @ W_dec + b_dec ----------------
// 64x64 tile, K=64 (single chunk). grid = (row tiles, col tiles).
__global__ __launch_bounds__(256) void dec_kernel(
    const float* __restrict__ pl, const float* __restrict__ W,
    const float* __restrict__ bias, float* __restrict__ out)
{
    __shared__ float At[64][68];   // pl^T tile
    __shared__ float Wt[64][64];
    const int tid = threadIdx.x;
    const int c0 = (tid & 15) * 4;
    const int r0 = (tid >> 4) * 4;
    const int row0 = blockIdx.x * 64;
    const int n0 = blockIdx.y * 64;

#pragma unroll
    for (int j = 0; j < 4; ++j) {
        int ft = tid + j * 256;
        int k4 = ft & 15, r = ft >> 4;
        float4 v = *(const float4*)(pl + (size_t)(row0 + r) * LAT_ + k4 * 4);
        At[k4 * 4 + 0][r] = v.x;
        At[k4 * 4 + 1][r] = v.y;
        At[k4 * 4 + 2][r] = v.z;
        At[k4 * 4 + 3][r] = v.w;
        int c4 = ft & 15, kk = ft >> 4;
        *(float4*)(&Wt[kk][c4 * 4]) =
            *(const float4*)(W + (size_t)kk * OBS_ + n0 + c4 * 4);
    }
    __syncthreads();

    float acc[4][4];
    float4 bv = *(const float4*)(bias + n0 + c0);
#pragma unroll
    for (int i = 0; i < 4; ++i) {
        acc[i][0] = bv.x; acc[i][1] = bv.y; acc[i][2] = bv.z; acc[i][3] = bv.w;
    }
#pragma unroll 4
    for (int kk = 0; kk < 64; ++kk) {
        float4 a = *(const float4*)(&At[kk][r0]);
        float4 w = *(const float4*)(&Wt[kk][c0]);
        acc[0][0] = fmaf(a.x, w.x, acc[0][0]); acc[0][1] = fmaf(a.x, w.y, acc[0][1]);
        acc[0][2] = fmaf(a.x, w.z, acc[0][2]); acc[0][3] = fmaf(a.x, w.w, acc[0][3]);
        acc[1][0] = fmaf(a.y, w.x, acc[1][0]); acc[1][1] = fmaf(a.y, w.y, acc[1][1]);
        acc[1][2] = fmaf(a.y, w.z, acc[1][2]); acc[1][3] = fmaf(a.y, w.w, acc[1][3]);
        acc[2][0] = fmaf(a.z, w.x, acc[2][0]); acc[2][1] = fmaf(a.z, w.y, acc[2][1]);
        acc[2][2] = fmaf(a.z, w.z, acc[2][2]); acc[2][3] = fmaf(a.z, w.w, acc[2][3]);
        acc[3][0] = fmaf(a.w, w.x, acc[3][0]); acc[3][1] = fmaf(a.w, w.y, acc[3][1]);
        acc[3][2] = fmaf(a.w, w.z, acc[3][2]); acc[3][3] = fmaf(a.w, w.w, acc[3][3]);
    }
#pragma unroll
    for (int i = 0; i < 4; ++i)
        *(float4*)(out + (size_t)(row0 + r0 + i) * OBS_ + n0 + c0) =
            make_float4(acc[i][0], acc[i][1], acc[i][2], acc[i][3]);
}

extern "C" void kernel_launch(void* const* d_in, const int* in_sizes, int n_in,
                              void* d_out, int out_size, void* d_ws, size_t ws_size,
                              hipStream_t stream)
{
    const float* obs  = (const float*)d_in[0];
    const float* act  = (const float*)d_in[1];
    const float* Wenc = (const float*)d_in[2];
    const float* benc = (const float*)d_in[3];
    const float* Wdec = (const float*)d_in[4];
    const float* bdec = (const float*)d_in[5];
    const float* Wphi = (const float*)d_in[6];
    const float* bphi = (const float*)d_in[7];

    float* out    = (float*)d_out;
    float* latent = out;
    float* rho    = out + RHO_OFF;
    float* pl     = out + PL_OFF;
    float* pobs   = out + POBS_OFF;

    // ws only needs pfx (compact local prefixes) + gws now: ~34 MB
    const size_t pfx_elems = (size_t)BTA_ * NB_ * 64;          // 8,355,840 floats
    const size_t gws_elems = 512ULL * NCH_ * 8;                // 131,072 floats
    const bool use_scan = (ws_size >= (pfx_elems + gws_elems) * sizeof(float));
    float* pfx = (float*)d_ws;
    float* gws = pfx + pfx_elems;

    // 1) encoder
    hipLaunchKernelGGL(enc_kernel, dim3(BT_ / 64), dim3(256), 0, stream,
                       obs, Wenc, benc, latent);

    // 2) phi + expm -> writes rho in full (blocks + zeros), no eb, no rho_write
    hipLaunchKernelGGL(phi_expm_kernel, dim3((BTA_ + 255) / 256, NB_), dim3(256), 0, stream,
                       act, Wphi, bphi, rho);

    // 3) recurrence (reads diag blocks out of rho, L2-hot)
    if (use_scan) {
        hipLaunchKernelGGL(scan_local_kernel, dim3(16384 / 64), dim3(64), 0, stream,
                           rho, pfx);
        hipLaunchKernelGGL(scan_chunk_kernel, dim3(8), dim3(64), 0, stream,
                           latent, pfx, gws, pl);
        hipLaunchKernelGGL(scan_emit_kernel, dim3(BTA_ * NB_ / 256), dim3(256), 0, stream,
                           pfx, gws, pl);
    } else {
        hipLaunchKernelGGL(recur_kernel, dim3(8), dim3(64), 0, stream,
                           latent, rho, pl);
    }

    // 4) decoder
    hipLaunchKernelGGL(dec_kernel, dim3(BT_ / 64, OBS_ / 64), dim3(256), 0, stream,
                       pl, Wdec, bdec, pobs);
}

// Round 4
// 508.119 us; speedup vs baseline: 1.3123x; 1.3123x over previous
//
#include <hip/hip_runtime.h>

#define B_    64
#define T_    256
#define TA_   255
#define OBS_  512
#define ACT_  32
#define LAT_  64
#define NB_   8
#define BS_   8
#define PHI_  512
#define BT_   16384
#define BTA_  16320
#define CH_   8
#define NCH_  32

// output layout (floats): latent | rho | predicted_latents | predicted_obs
#define RHO_OFF   1048576ULL
#define PL_OFF    67895296ULL
#define POBS_OFF  68943872ULL

typedef float f32x4 __attribute__((ext_vector_type(4)));

// ---------------- encoder: latent = obs @ W_enc + b_enc ----------------
// 64x64 output tile, K chunked by 64 through LDS. Per-lane (divergent)
// addresses everywhere -> vector loads (round-1 lesson: wave-uniform
// addresses become s_load and thrash the scalar cache at 33 MB).
__global__ __launch_bounds__(256) void enc_kernel(
    const float* __restrict__ obs, const float* __restrict__ W,
    const float* __restrict__ bias, float* __restrict__ latent)
{
    __shared__ float At[64][68];   // At[k][row], pad 68: read = 2-way (free)
    __shared__ float Wt[64][64];   // Wt[k][col]
    const int tid = threadIdx.x;
    const int c0 = (tid & 15) * 4;
    const int r0 = (tid >> 4) * 4;
    const int row0 = blockIdx.x * 64;

    float4 pa[4], pw[4];
    // prefetch chunk 0
#pragma unroll
    for (int j = 0; j < 4; ++j) {
        int ft = tid + j * 256;
        int k4 = ft & 15, r = ft >> 4;
        pa[j] = *(const float4*)(obs + (size_t)(row0 + r) * OBS_ + k4 * 4);
        int c4 = ft & 15, kk = ft >> 4;
        pw[j] = *(const float4*)(W + (size_t)kk * LAT_ + c4 * 4);
    }

    float acc[4][4];
    float4 bv = *(const float4*)(bias + c0);
#pragma unroll
    for (int i = 0; i < 4; ++i) {
        acc[i][0] = bv.x; acc[i][1] = bv.y; acc[i][2] = bv.z; acc[i][3] = bv.w;
    }

    for (int kc = 0; kc < OBS_; kc += 64) {
#pragma unroll
        for (int j = 0; j < 4; ++j) {
            int ft = tid + j * 256;
            int k4 = ft & 15, r = ft >> 4;
            At[k4 * 4 + 0][r] = pa[j].x;
            At[k4 * 4 + 1][r] = pa[j].y;
            At[k4 * 4 + 2][r] = pa[j].z;
            At[k4 * 4 + 3][r] = pa[j].w;
            int c4 = ft & 15, kk = ft >> 4;
            *(float4*)(&Wt[kk][c4 * 4]) = pw[j];
        }
        __syncthreads();
        if (kc + 64 < OBS_) {
            // prefetch next chunk while computing this one
#pragma unroll
            for (int j = 0; j < 4; ++j) {
                int ft = tid + j * 256;
                int k4 = ft & 15, r = ft >> 4;
                pa[j] = *(const float4*)(obs + (size_t)(row0 + r) * OBS_ + kc + 64 + k4 * 4);
                int c4 = ft & 15, kk = ft >> 4;
                pw[j] = *(const float4*)(W + (size_t)(kc + 64 + kk) * LAT_ + c4 * 4);
            }
        }
#pragma unroll 4
        for (int kk = 0; kk < 64; ++kk) {
            float4 a = *(const float4*)(&At[kk][r0]);
            float4 w = *(const float4*)(&Wt[kk][c0]);
            acc[0][0] = fmaf(a.x, w.x, acc[0][0]); acc[0][1] = fmaf(a.x, w.y, acc[0][1]);
            acc[0][2] = fmaf(a.x, w.z, acc[0][2]); acc[0][3] = fmaf(a.x, w.w, acc[0][3]);
            acc[1][0] = fmaf(a.y, w.x, acc[1][0]); acc[1][1] = fmaf(a.y, w.y, acc[1][1]);
            acc[1][2] = fmaf(a.y, w.z, acc[1][2]); acc[1][3] = fmaf(a.y, w.w, acc[1][3]);
            acc[2][0] = fmaf(a.z, w.x, acc[2][0]); acc[2][1] = fmaf(a.z, w.y, acc[2][1]);
            acc[2][2] = fmaf(a.z, w.z, acc[2][2]); acc[2][3] = fmaf(a.z, w.w, acc[2][3]);
            acc[3][0] = fmaf(a.w, w.x, acc[3][0]); acc[3][1] = fmaf(a.w, w.y, acc[3][1]);
            acc[3][2] = fmaf(a.w, w.z, acc[3][2]); acc[3][3] = fmaf(a.w, w.w, acc[3][3]);
        }
        __syncthreads();
    }
#pragma unroll
    for (int i = 0; i < 4; ++i)
        *(float4*)(latent + (size_t)(row0 + r0 + i) * LAT_ + c0) =
            make_float4(acc[i][0], acc[i][1], acc[i][2], acc[i][3]);
}

// ---------------- 8x8 matmul in registers ----------------
__device__ __forceinline__ void mm8(float* __restrict__ D,
                                    const float* __restrict__ X,
                                    const float* __restrict__ Y)
{
#pragma unroll
    for (int r = 0; r < 8; ++r)
#pragma unroll
        for (int c = 0; c < 8; ++c) {
            float s = 0.f;
#pragma unroll
            for (int q = 0; q < 8; ++q) s = fmaf(X[r * 8 + q], Y[q * 8 + c], s);
            D[r * 8 + c] = s;
        }
}

// ---------------- phi GEMM + expm, one 8x8 block per thread ----------------
// In-place Horner via right-multiply (A and p(A) commute).
// R7 post-mortem lesson (R5/R6): per-lane scattered 16B stores at 16KB
// lane stride = one 128B line-fill per 16B store (FETCH 1.9GB, 8x write
// amp) REGARDLESS of nt hint -- partial-line write misses write-allocate.
// fillBufferAligned (WRITE 1.2GB, FETCH 14.5KB) proves lane-coalesced
// full-line stores skip the fill. So: stage the 8x8 results in LDS,
// barrier, then write rho with consecutive lanes -> consecutive float4s
// (each store instruction covers 8 full 128B lines).
__global__ __launch_bounds__(256, 1) void phi_expm_kernel(
    const float* __restrict__ act, const float* __restrict__ Wp,
    const float* __restrict__ bp, float* __restrict__ rho)
{
    __shared__ float S[256][68];   // 68-pad: even bank spread both phases
    const int bt = blockIdx.x * 256 + threadIdx.x;
    const int k  = blockIdx.y;

    if (bt < BTA_) {
        float A[64];
        {
            const float* bpp = bp + k * 64;
#pragma unroll
            for (int p = 0; p < 64; ++p) A[p] = bpp[p];
        }
        const float4* arow4 = (const float4*)(act + (size_t)bt * ACT_);
        const float* wk = Wp + k * 64;
#pragma unroll
        for (int a4 = 0; a4 < ACT_ / 4; ++a4) {
            float4 av = arow4[a4];
            const float* wr = wk + (size_t)(a4 * 4) * PHI_;
#pragma unroll
            for (int p = 0; p < 64; ++p) A[p] = fmaf(av.x, wr[p], A[p]);
            wr += PHI_;
#pragma unroll
            for (int p = 0; p < 64; ++p) A[p] = fmaf(av.y, wr[p], A[p]);
            wr += PHI_;
#pragma unroll
            for (int p = 0; p < 64; ++p) A[p] = fmaf(av.z, wr[p], A[p]);
            wr += PHI_;
#pragma unroll
            for (int p = 0; p < 64; ++p) A[p] = fmaf(av.w, wr[p], A[p]);
        }

        // in-place scale+transpose: A <- (block^T)/8 (reference transposes
        // blocks; scaling-and-squaring with s=3)
#pragma unroll
        for (int r = 0; r < 8; ++r) {
            A[r * 9] *= 0.125f;
#pragma unroll
            for (int c = r + 1; c < 8; ++c) {
                float t = A[r * 8 + c];
                A[r * 8 + c] = 0.125f * A[c * 8 + r];
                A[c * 8 + r] = 0.125f * t;
            }
        }

        // degree-7 Taylor, Horner with right-multiply, P updated IN PLACE:
        // P = A/7! + I/6!; then 6x (P = P*A + c I), c = 1/120,1/24,1/6,1/2,1,1
        float P[64];
#pragma unroll
        for (int i = 0; i < 64; ++i) P[i] = (1.f / 5040.f) * A[i];
#pragma unroll
        for (int d = 0; d < 8; ++d) P[d * 9] += 1.f / 720.f;

        constexpr float COEF[6] = {1.f/120.f, 1.f/24.f, 1.f/6.f, 0.5f, 1.f, 1.f};
#pragma unroll
        for (int it = 0; it < 6; ++it) {
            const float coef = COEF[it];
#pragma unroll
            for (int r = 0; r < 8; ++r) {
                float t[8];
#pragma unroll
                for (int c = 0; c < 8; ++c) {
                    float s = 0.f;
#pragma unroll
                    for (int q = 0; q < 8; ++q) s = fmaf(P[r * 8 + q], A[q * 8 + c], s);
                    t[c] = s;
                }
#pragma unroll
                for (int c = 0; c < 8; ++c) P[r * 8 + c] = t[c];
                P[r * 9] += coef;
            }
        }

        // 3 squarings, ping-pong (A dead; T reuses its registers): result in T
        float T[64];
        mm8(T, P, P);
        mm8(P, T, T);
        mm8(T, P, P);

#pragma unroll
        for (int q = 0; q < 16; ++q) {
            f32x4 v = {T[4*q], T[4*q+1], T[4*q+2], T[4*q+3]};
            *(f32x4*)(&S[threadIdx.x][q * 4]) = v;
        }
    }
    __syncthreads();

    // coalesced write phase: each wave writes 64 bt-regions (2KB each:
    // rows k*8..k*8+8 of rho[bt], zeros except the diag block). float4
    // index f = half*64 + lane -> row = f>>4, c4 = f&15: consecutive
    // lanes -> consecutive 16B -> full 128B lines per instruction.
    const int lane = threadIdx.x & 63;
    const int w    = threadIdx.x >> 6;
    const int bt0  = blockIdx.x * 256;
    const int c4   = lane & 15;
    const int rsub = lane >> 4;           // 0..3
    for (int rg = 0; rg < 64; ++rg) {
        const int btl = w * 64 + rg;
        const int btg = bt0 + btl;
        if (btg >= BTA_) break;           // wave-uniform (w, rg uniform)
        float* base = rho + ((size_t)btg * LAT_ + (size_t)(k * BS_)) * LAT_;
#pragma unroll
        for (int half = 0; half < 2; ++half) {
            const int row = half * 4 + rsub;
            f32x4 v = {0.f, 0.f, 0.f, 0.f};
            if (c4 == 2 * k)
                v = *(const f32x4*)(&S[btl][row * 8]);
            else if (c4 == 2 * k + 1)
                v = *(const f32x4*)(&S[btl][row * 8 + 4]);
            *(f32x4*)(base + (size_t)row * LAT_ + c4 * 4) = v;
        }
    }
}

// ---------------- 8x8 block load from strided rows ----------------
__device__ __forceinline__ void load_block8(float* __restrict__ dst,
                                            const float* __restrict__ p, int rs)
{
#pragma unroll
    for (int r = 0; r < 8; ++r) {
        float4 x = *(const float4*)(p + (size_t)r * rs);
        float4 y = *(const float4*)(p + (size_t)r * rs + 4);
        dst[r*8+0] = x.x; dst[r*8+1] = x.y; dst[r*8+2] = x.z; dst[r*8+3] = x.w;
        dst[r*8+4] = y.x; dst[r*8+5] = y.y; dst[r*8+6] = y.z; dst[r*8+7] = y.w;
    }
}

// ======== parallel scan over the recurrence h_{t+1} = h_t * M_t ========
// Phase A: per (b,k,chunk) local prefix products L_i = M_{t0}...M_{t0+i}
// (64,1) keeps the 512-VGPR cap (~150 live). Reads the diag blocks
// straight out of rho; 256 blocks x 64 so all 256 CUs participate.
// pfx stays COMPACT (64 floats/block) so phases B/C keep dense reads.
#define SL_BODY_(I)                                                           \
    {                                                                         \
        float M[64];                                                          \
        load_block8(M, src + (size_t)(I) * 4096, LAT_);                       \
        _Pragma("unroll")                                                     \
        for (int r = 0; r < 8; ++r) {                                         \
            float tmp[8];                                                     \
            _Pragma("unroll")                                                 \
            for (int c = 0; c < 8; ++c) {                                     \
                float s = 0.f;                                                \
                _Pragma("unroll")                                             \
                for (int q = 0; q < 8; ++q)                                   \
                    s = fmaf(R[r * 8 + q], M[q * 8 + c], s);                  \
                tmp[c] = s;                                                   \
            }                                                                 \
            _Pragma("unroll")                                                 \
            for (int c = 0; c < 8; ++c) R[r * 8 + c] = tmp[c];                \
        }                                                                     \
        float* dp = dst + (size_t)(I) * 512;                                  \
        _Pragma("unroll")                                                     \
        for (int q = 0; q < 16; ++q) ((float4*)dp)[q] = ((const float4*)R)[q];\
    }

__global__ __launch_bounds__(64, 1) void scan_local_kernel(
    const float* __restrict__ rho, float* __restrict__ pfx)
{
    const int tid = blockIdx.x * 64 + threadIdx.x;   // 16384 threads
    const int k = tid & 7;
    const int j = (tid >> 3) & 31;
    const int b = tid >> 8;
    const int t0 = j * CH_;
    const int cnt = (TA_ - t0 < CH_) ? (TA_ - t0) : CH_;   // 8 (7 for last chunk)
    // diag block top-left of rho[b, t0], block k
    const float* src = rho + (size_t)(b * TA_ + t0) * 4096 + (size_t)k * (BS_ * LAT_ + BS_);
    float*       dst = pfx + ((size_t)(b * TA_ + t0) * 8 + k) * 64;

    float R[64];
    load_block8(R, src, LAT_);
#pragma unroll
    for (int q = 0; q < 16; ++q) ((float4*)dst)[q] = ((const float4*)R)[q];

    if (cnt == CH_) {
#pragma unroll
        for (int i = 1; i < CH_; ++i) SL_BODY_(i);
    } else {
#pragma unroll
        for (int i = 1; i < CH_ - 1; ++i) SL_BODY_(i);   // cnt is always 7 here
    }
}
#undef SL_BODY_

// Phase B: per (b,k) scan of chunk totals -> g_j = h0 * M_0..M_{CH*j-1}; pl[:,0]
// (64,1): live C+Cn+g ~= 140 regs needs the 512 cap too. Next-chunk prefetch.
__global__ __launch_bounds__(64, 1) void scan_chunk_kernel(
    const float* __restrict__ latent, const float* __restrict__ pfx,
    float* __restrict__ gws, float* __restrict__ pl)
{
    const int tid = blockIdx.x * 64 + threadIdx.x;   // 512 threads
    const int k = tid & 7, b = tid >> 3;
    float g[8];
    const float* l0 = latent + (size_t)b * T_ * LAT_ + k * 8;
#pragma unroll
    for (int m = 0; m < 8; ++m) g[m] = l0[m];

    float* pl0 = pl + (size_t)b * T_ * LAT_ + k * 8;
    *(float4*)(pl0)     = make_float4(g[0], g[1], g[2], g[3]);
    *(float4*)(pl0 + 4) = make_float4(g[4], g[5], g[6], g[7]);

    float* gp = gws + ((size_t)(b * NCH_) * 8 + k) * 8;
    *(float4*)(gp)     = make_float4(g[0], g[1], g[2], g[3]);
    *(float4*)(gp + 4) = make_float4(g[4], g[5], g[6], g[7]);

    float C[64];
    {
        const float* cp = pfx + ((size_t)(b * TA_ + CH_ - 1) * 8 + k) * 64;
#pragma unroll
        for (int q = 0; q < 16; ++q) ((float4*)C)[q] = ((const float4*)cp)[q];
    }
    for (int j = 1; j < NCH_; ++j) {
        float Cn[64];
        if (j + 1 < NCH_) {
            const float* cp = pfx + ((size_t)(b * TA_ + (j + 1) * CH_ - 1) * 8 + k) * 64;
#pragma unroll
            for (int q = 0; q < 16; ++q) ((float4*)Cn)[q] = ((const float4*)cp)[q];
        }
        float ng[8];
#pragma unroll
        for (int m = 0; m < 8; ++m) {
            float s = 0.f;
#pragma unroll
            for (int l = 0; l < 8; ++l) s = fmaf(g[l], C[l * 8 + m], s);
            ng[m] = s;
        }
#pragma unroll
        for (int m = 0; m < 8; ++m) g[m] = ng[m];
        float* gq = gws + ((size_t)(b * NCH_ + j) * 8 + k) * 8;
        *(float4*)(gq)     = make_float4(g[0], g[1], g[2], g[3]);
        *(float4*)(gq + 4) = make_float4(g[4], g[5], g[6], g[7]);
#pragma unroll
        for (int q = 0; q < 64; ++q) C[q] = Cn[q];
    }
}

// Phase C: per (b,t,k): h_t = g_j * L_{j,i}  -> pl[b,t+1,k*8..]
__global__ __launch_bounds__(256, 1) void scan_emit_kernel(
    const float* __restrict__ pfx, const float* __restrict__ gws,
    float* __restrict__ pl)
{
    const int tid = blockIdx.x * 256 + threadIdx.x;   // 130560 threads
    const int k = tid & 7;
    const int bt = tid >> 3;            // 0..16319
    const int b = bt / TA_;
    const int t = bt - b * TA_;
    const int j = t >> 3;               // CH_ = 8

    float g[8];
    const float* gp = gws + ((size_t)(b * NCH_ + j) * 8 + k) * 8;
    *(float4*)(g)     = *(const float4*)(gp);
    *(float4*)(g + 4) = *(const float4*)(gp + 4);

    const float* lp = pfx + ((size_t)bt * 8 + k) * 64;
    float L[64];
#pragma unroll
    for (int q = 0; q < 16; ++q) ((float4*)L)[q] = ((const float4*)lp)[q];

    float h[8];
#pragma unroll
    for (int m = 0; m < 8; ++m) {
        float s = 0.f;
#pragma unroll
        for (int l = 0; l < 8; ++l) s = fmaf(g[l], L[l * 8 + m], s);
        h[m] = s;
    }
    float* op = pl + ((size_t)b * T_ + t + 1) * LAT_ + k * 8;
    *(float4*)(op)     = make_float4(h[0], h[1], h[2], h[3]);
    *(float4*)(op + 4) = make_float4(h[4], h[5], h[6], h[7]);
}

// ---------------- sequential recurrence (fallback for small ws) ----------------
// reads the diag blocks straight out of rho (always valid now)
__global__ __launch_bounds__(64) void recur_kernel(
    const float* __restrict__ latent, const float* __restrict__ rho,
    float* __restrict__ pl)
{
    const int tid = blockIdx.x * 64 + threadIdx.x;   // 0..511
    const int b = tid >> 3, k = tid & 7;
    const float* e = rho + (size_t)b * ((size_t)TA_ * 4096) + (size_t)k * (BS_ * LAT_ + BS_);

    float h[8];
    const float* l0 = latent + (size_t)b * T_ * LAT_ + k * 8;
#pragma unroll
    for (int j = 0; j < 8; ++j) h[j] = l0[j];
    float* plp = pl + (size_t)b * T_ * LAT_ + k * 8;
    *(float4*)(plp)     = make_float4(h[0], h[1], h[2], h[3]);
    *(float4*)(plp + 4) = make_float4(h[4], h[5], h[6], h[7]);

    float eA[64], eB[64];
    load_block8(eA, e, LAT_);

#define STEP_(EBUF)                                                          \
    {                                                                        \
        float nh[8];                                                         \
        _Pragma("unroll")                                                    \
        for (int c = 0; c < 8; ++c) {                                        \
            float s = 0.f;                                                   \
            _Pragma("unroll")                                                \
            for (int r = 0; r < 8; ++r) s = fmaf(h[r], EBUF[r * 8 + c], s);  \
            nh[c] = s;                                                       \
        }                                                                    \
        plp += LAT_;                                                         \
        *(float4*)(plp)     = make_float4(nh[0], nh[1], nh[2], nh[3]);       \
        *(float4*)(plp + 4) = make_float4(nh[4], nh[5], nh[6], nh[7]);       \
        _Pragma("unroll")                                                    \
        for (int j = 0; j < 8; ++j) h[j] = nh[j];                            \
    }

    for (int t = 0; t < TA_; t += 2) {
        int tn = (t + 1 < TA_) ? t + 1 : TA_ - 1;
        load_block8(eB, e + (size_t)tn * 4096, LAT_);
        STEP_(eA);
        if (t + 1 >= TA_) break;
        int tn2 = (t + 2 < TA_) ? t + 2 : TA_ - 1;
        load_block8(eA, e + (size_t)tn2 * 4096, LAT_);
        STEP_(eB);
    }
#undef STEP_
}

// ---------------- decoder: pobs = pl @ W_dec + b_dec ----------------
// 64x64 tile, K=64 (single chunk). grid = (row tiles, col tiles).
__global__ __launch_bounds__(256) void dec_kernel(
    const float* __restrict__ pl, const float* __restrict__ W,
    const float* __restrict__ bias, float* __restrict__ out)
{
    __shared__ float At[64][68];   // pl^T tile
    __shared__ float Wt[64][64];
    const int tid = threadIdx.x;
    const int c0 = (tid & 15) * 4;
    const int r0 = (tid >> 4) * 4;
    const int row0 = blockIdx.x * 64;
    const int n0 = blockIdx.y * 64;

#pragma unroll
    for (int j = 0; j < 4; ++j) {
        int ft = tid + j * 256;
        int k4 = ft & 15, r = ft >> 4;
        float4 v = *(const float4*)(pl + (size_t)(row0 + r) * LAT_ + k4 * 4);
        At[k4 * 4 + 0][r] = v.x;
        At[k4 * 4 + 1][r] = v.y;
        At[k4 * 4 + 2][r] = v.z;
        At[k4 * 4 + 3][r] = v.w;
        int c4 = ft & 15, kk = ft >> 4;
        *(float4*)(&Wt[kk][c4 * 4]) =
            *(const float4*)(W + (size_t)kk * OBS_ + n0 + c4 * 4);
    }
    __syncthreads();

    float acc[4][4];
    float4 bv = *(const float4*)(bias + n0 + c0);
#pragma unroll
    for (int i = 0; i < 4; ++i) {
        acc[i][0] = bv.x; acc[i][1] = bv.y; acc[i][2] = bv.z; acc[i][3] = bv.w;
    }
#pragma unroll 4
    for (int kk = 0; kk < 64; ++kk) {
        float4 a = *(const float4*)(&At[kk][r0]);
        float4 w = *(const float4*)(&Wt[kk][c0]);
        acc[0][0] = fmaf(a.x, w.x, acc[0][0]); acc[0][1] = fmaf(a.x, w.y, acc[0][1]);
        acc[0][2] = fmaf(a.x, w.z, acc[0][2]); acc[0][3] = fmaf(a.x, w.w, acc[0][3]);
        acc[1][0] = fmaf(a.y, w.x, acc[1][0]); acc[1][1] = fmaf(a.y, w.y, acc[1][1]);
        acc[1][2] = fmaf(a.y, w.z, acc[1][2]); acc[1][3] = fmaf(a.y, w.w, acc[1][3]);
        acc[2][0] = fmaf(a.z, w.x, acc[2][0]); acc[2][1] = fmaf(a.z, w.y, acc[2][1]);
        acc[2][2] = fmaf(a.z, w.z, acc[2][2]); acc[2][3] = fmaf(a.z, w.w, acc[2][3]);
        acc[3][0] = fmaf(a.w, w.x, acc[3][0]); acc[3][1] = fmaf(a.w, w.y, acc[3][1]);
        acc[3][2] = fmaf(a.w, w.z, acc[3][2]); acc[3][3] = fmaf(a.w, w.w, acc[3][3]);
    }
#pragma unroll
    for (int i = 0; i < 4; ++i)
        *(float4*)(out + (size_t)(row0 + r0 + i) * OBS_ + n0 + c0) =
            make_float4(acc[i][0], acc[i][1], acc[i][2], acc[i][3]);
}

extern "C" void kernel_launch(void* const* d_in, const int* in_sizes, int n_in,
                              void* d_out, int out_size, void* d_ws, size_t ws_size,
                              hipStream_t stream)
{
    const float* obs  = (const float*)d_in[0];
    const float* act  = (const float*)d_in[1];
    const float* Wenc = (const float*)d_in[2];
    const float* benc = (const float*)d_in[3];
    const float* Wdec = (const float*)d_in[4];
    const float* bdec = (const float*)d_in[5];
    const float* Wphi = (const float*)d_in[6];
    const float* bphi = (const float*)d_in[7];

    float* out    = (float*)d_out;
    float* latent = out;
    float* rho    = out + RHO_OFF;
    float* pl     = out + PL_OFF;
    float* pobs   = out + POBS_OFF;

    // ws only needs pfx (compact local prefixes) + gws now: ~34 MB
    const size_t pfx_elems = (size_t)BTA_ * NB_ * 64;          // 8,355,840 floats
    const size_t gws_elems = 512ULL * NCH_ * 8;                // 131,072 floats
    const bool use_scan = (ws_size >= (pfx_elems + gws_elems) * sizeof(float));
    float* pfx = (float*)d_ws;
    float* gws = pfx + pfx_elems;

    // 1) encoder
    hipLaunchKernelGGL(enc_kernel, dim3(BT_ / 64), dim3(256), 0, stream,
                       obs, Wenc, benc, latent);

    // 2) phi + expm -> writes rho in full (LDS-staged, lane-coalesced)
    hipLaunchKernelGGL(phi_expm_kernel, dim3((BTA_ + 255) / 256, NB_), dim3(256), 0, stream,
                       act, Wphi, bphi, rho);

    // 3) recurrence (reads diag blocks out of rho)
    if (use_scan) {
        hipLaunchKernelGGL(scan_local_kernel, dim3(16384 / 64), dim3(64), 0, stream,
                           rho, pfx);
        hipLaunchKernelGGL(scan_chunk_kernel, dim3(8), dim3(64), 0, stream,
                           latent, pfx, gws, pl);
        hipLaunchKernelGGL(scan_emit_kernel, dim3(BTA_ * NB_ / 256), dim3(256), 0, stream,
                           pfx, gws, pl);
    } else {
        hipLaunchKernelGGL(recur_kernel, dim3(8), dim3(64), 0, stream,
                           latent, rho, pl);
    }

    // 4) decoder
    hipLaunchKernelGGL(dec_kernel, dim3(BT_ / 64, OBS_ / 64), dim3(256), 0, stream,
                       pl, Wdec, bdec, pobs);
}